// Round 9
// baseline (19753.889 us; speedup 1.0000x reference)
//
#include <hip/hip_runtime.h>

static constexpr int NBLD = 100000, NCOM = 10000, EBU = 400000, ECO = 80000;
static constexpr int EBT = EBU + NBLD;   // 500000 (with self loops)
static constexpr int ECT = ECO + NCOM;   //  90000

// ---- workspace layout (bytes). Peak ~195.2 MB ----
static constexpr size_t OFF_XL2  = 0;
static constexpr size_t OFF_XR2  = 51200000;
static constexpr size_t OFF_XLH  = 102400000;
static constexpr size_t OFF_XRH  = 128000000;
static constexpr size_t OFF_X1C  = 153600000;
static constexpr size_t OFF_X2   = 102400000;
static constexpr size_t OFF_CXL  = 0;
static constexpr size_t OFF_CXR  = 20480000;
static constexpr size_t OFF_CX1  = 40960000;
static constexpr size_t OFF_CX2L = 61440000;
static constexpr size_t OFF_CX2R = 66560000;
static constexpr size_t OFF_LOGC = 72000000;
static constexpr size_t OFF_MC   = 74880000;
static constexpr size_t OFF_DC   = 75200000;
static constexpr size_t OFF_LOG2 = 153600000;
static constexpr size_t OFF_M2   = 161600000;
static constexpr size_t OFF_D2   = 163200000;
static constexpr size_t OFF_CX2F = 179200000;
static constexpr size_t OFF_WM   = 184320000;
static constexpr size_t OFF_XL3  = 185120000;
static constexpr size_t OFF_XR3  = 185920000;
static constexpr size_t OFF_BOFF = 186720000;
static constexpr size_t OFF_BCUR = 187120016;
static constexpr size_t OFF_BSRC = 187520016;
static constexpr size_t OFF_COFF = 189520016;
static constexpr size_t OFF_CCUR = 189560032;
static constexpr size_t OFF_CSRC = 189600032;
static constexpr size_t OFF_LOG1 = 189960032;
static constexpr size_t OFF_M1   = 191960032;
static constexpr size_t OFF_D1   = 192360032;
static constexpr size_t OFF_BDST = 192760032;
static constexpr size_t OFF_CDST = 194760032;
static constexpr size_t OFF_STAT = 195200032;   // 4 ints
// end: ~195,200,048

// ================= small utils =================
__global__ void k_zero(int* __restrict__ p, int n) {
  int i = blockIdx.x * blockDim.x + threadIdx.x;
  if (i < n) p[i] = 0;
}

// ================= CSR build =================
__global__ void k_count(const int* __restrict__ dsti, int Eg, int Et, int* __restrict__ cnt) {
  int e = blockIdx.x * blockDim.x + threadIdx.x;
  if (e >= Et) return;
  int dst = (e < Eg) ? dsti[e] : (e - Eg);
  atomicAdd(&cnt[dst], 1);
}

__global__ void k_scan_block(const int* __restrict__ cnt, int N, int* __restrict__ off) {
  __shared__ int sh[256];
  __shared__ int carry;
  int tid = threadIdx.x;
  if (tid == 0) carry = 0;
  __syncthreads();
  for (int base = 0; base < N; base += 256) {
    int i = base + tid;
    int v = (i < N) ? cnt[i] : 0;
    sh[tid] = v;
    __syncthreads();
    for (int o = 1; o < 256; o <<= 1) {
      int t = (tid >= o) ? sh[tid - o] : 0;
      __syncthreads();
      sh[tid] += t;
      __syncthreads();
    }
    if (i < N) off[i] = carry + sh[tid] - v;
    __syncthreads();
    if (tid == 255) carry += sh[255];
    __syncthreads();
  }
  if (tid == 0) off[N] = carry;
}

__global__ void k_copycur(const int* __restrict__ off, int* __restrict__ cur, int N) {
  int i = blockIdx.x * blockDim.x + threadIdx.x;
  if (i < N) cur[i] = off[i];
}

__global__ void k_scatter(const int* __restrict__ srci, const int* __restrict__ dsti, int Eg, int Et,
                          int* __restrict__ cur, int* __restrict__ srcl, int* __restrict__ dstl) {
  int e = blockIdx.x * blockDim.x + threadIdx.x;
  if (e >= Et) return;
  int src, dst;
  if (e < Eg) { src = srci[e]; dst = dsti[e]; } else { src = dst = e - Eg; }
  int pos = atomicAdd(&cur[dst], 1);
  srcl[pos] = src;
  dstl[pos] = dst;
}

// ===== naive GEMM: out[n,j] = sum_k A(n,k) * W[k*ldw + j]  (ALL FLOAT32) =====
// AMODE: 0 plain A (af32,lda); 2 fused on-the-fly (K=192):
//        k<64 -> bfeat[n,k]*w0, else cx2f[map[n], k-64]*w1 (wm==nullptr -> 1)
// PAIR: N=128; j<64 from W0 -> out0; j>=64 from W1 -> out1 (ld 64)
// ACCUM (non-PAIR only): out0 +=
template<int AMODE, bool PAIR, bool ACCUM>
__global__ void k_gemm_lit(const float* __restrict__ af32,
                           const float* __restrict__ bfeat, const float* __restrict__ cx2f,
                           const int* __restrict__ map, const float* __restrict__ wm,
                           const float* __restrict__ W0, const float* __restrict__ W1,
                           float* __restrict__ out0, float* __restrict__ out1,
                           int M, int K, int lda, int ldw, int N) {
  long long idx = (long long)blockIdx.x * blockDim.x + threadIdx.x;
  int n = (int)(idx / N);
  int j = (int)(idx - (long long)n * N);
  if (n >= M) return;
  int mrow = 0; float w0f = 1.f, w1f = 1.f;
  if (AMODE == 2) {
    mrow = map[n];
    if (wm != nullptr) { w0f = wm[(size_t)n * 2]; w1f = wm[(size_t)n * 2 + 1]; }
  }
  const float* Wp; int jj;
  if (PAIR) {
    if (j < 64) { Wp = W0; jj = j; } else { Wp = W1; jj = j - 64; }
  } else { Wp = W0; jj = j; }
  float acc = 0.f;
  for (int k = 0; k < K; ++k) {
    float a;
    if (AMODE == 0) a = af32[(size_t)n * lda + k];
    else a = (k < 64) ? bfeat[(size_t)n * 64 + k] * w0f
                      : cx2f[(size_t)mrow * 128 + (k - 64)] * w1f;
    acc = fmaf(a, Wp[(size_t)k * ldw + jj], acc);
  }
  if (PAIR) {
    float* op = (j < 64) ? out0 : out1;
    op[(size_t)n * 64 + jj] = acc;
  } else {
    size_t oi = (size_t)n * N + j;
    out0[oi] = ACCUM ? (out0[oi] + acc) : acc;
  }
}

// ===== literal two-pass GATv2 =====
template<int H, int D>
__global__ void k_logit(const float* __restrict__ xl, const float* __restrict__ xr,
                        const float* __restrict__ att,
                        const int* __restrict__ srcl, const int* __restrict__ dstl,
                        float* __restrict__ logit, int E, int ld) {
  int p = blockIdx.x * blockDim.x + threadIdx.x;
  if (p >= E) return;
  int s = srcl[p], t = dstl[p];
#pragma unroll 1
  for (int h = 0; h < H; ++h) {
    float acc = 0.f;
    for (int d = 0; d < D; ++d) {
      int c = h * D + d;
      float v = xl[(size_t)s * ld + c] + xr[(size_t)t * ld + c];
      v = v > 0.f ? v : 0.2f * v;
      acc = fmaf(v, att[c], acc);
    }
    logit[(size_t)p * H + h] = acc;
  }
}

template<int H>
__global__ void k_segmax(const float* __restrict__ logit, const int* __restrict__ off,
                         float* __restrict__ Mx, int N) {
  int n = blockIdx.x * blockDim.x + threadIdx.x;
  if (n >= N) return;
  int p0 = off[n], p1 = off[n + 1];
#pragma unroll 1
  for (int h = 0; h < H; ++h) {
    float m = -INFINITY;
    for (int p = p0; p < p1; ++p) m = fmaxf(m, logit[(size_t)p * H + h]);
    Mx[(size_t)n * H + h] = m;
  }
}

template<int H>
__global__ void k_segden(const float* __restrict__ logit, const int* __restrict__ off,
                         const float* __restrict__ Mx, float* __restrict__ den, int N) {
  int n = blockIdx.x * blockDim.x + threadIdx.x;
  if (n >= N) return;
  int p0 = off[n], p1 = off[n + 1];
#pragma unroll 1
  for (int h = 0; h < H; ++h) {
    float m = Mx[(size_t)n * H + h];
    float s = 0.f;
    for (int p = p0; p < p1; ++p) s += __expf(logit[(size_t)p * H + h] - m);
    den[(size_t)n * H + h] = s;
  }
}

template<int H, int D, int V, bool RELU>
__global__ __launch_bounds__(256) void k_agg(const float* __restrict__ xl,
                                             const float* __restrict__ logit,
                                             const int* __restrict__ off, const int* __restrict__ srcl,
                                             const float* __restrict__ Mx, const float* __restrict__ den,
                                             const float* __restrict__ bias,
                                             float* __restrict__ outp, int N, int ld) {
  int n = (int)((blockIdx.x * (unsigned)blockDim.x + threadIdx.x) >> 6);
  if (n >= N) return;
  int lane = threadIdx.x & 63;
  int base = lane * V;
  float acc[V], mh[V], dh[V];
#pragma unroll
  for (int j = 0; j < V; ++j) {
    int h = (base + j) / D;
    mh[j] = Mx[(size_t)n * H + h];
    dh[j] = den[(size_t)n * H + h];
    acc[j] = 0.f;
  }
  int p0 = off[n], p1 = off[n + 1];
  for (int p = p0; p < p1; ++p) {
    int s = srcl[p];
#pragma unroll
    for (int j = 0; j < V; ++j) {
      int h = (base + j) / D;
      float pe = __expf(logit[(size_t)p * H + h] - mh[j]);
      acc[j] = fmaf(pe, xl[(size_t)s * ld + base + j], acc[j]);
    }
  }
#pragma unroll
  for (int j = 0; j < V; ++j) {
    float v = acc[j] / dh[j] + bias[base + j];
    if (RELU) v = fmaxf(v, 0.f);
    outp[(size_t)n * ld + base + j] = v;
  }
}

// ===== literal feature attention =====
__global__ __launch_bounds__(256) void k_fa_lit(const float* __restrict__ bfeat,
                                                const float* __restrict__ cx2f, const int* __restrict__ map,
                                                const float* __restrict__ w1, const float* __restrict__ b1,
                                                const float* __restrict__ w2, const float* __restrict__ b2,
                                                float* __restrict__ wm, int NB) {
  __shared__ float comb[4][192];
  int widx = threadIdx.x >> 6;
  int n = blockIdx.x * 4 + widx;
  int lane = threadIdx.x & 63;
  float* cb = comb[widx];
  int m = map[n];
  for (int t = lane; t < 192; t += 64)
    cb[t] = (t < 64) ? bfeat[(size_t)n * 64 + t] : cx2f[(size_t)m * 128 + (t - 64)];
  __syncthreads();
  float wa0 = 0.f, wa1 = 0.f;
#pragma unroll 1
  for (int h = 0; h < 8; ++h) {
    float l0 = 0.f, l1 = 0.f;
#pragma unroll
    for (int kk = 0; kk < 2; ++kk) {
      int k = lane + kk * 64;
      float acc = b1[h * 128 + k];
      const float* wrow = w1 + (size_t)h * 192 * 128 + k;
      for (int f = 0; f < 192; ++f)
        acc = fmaf(cb[f], wrow[(size_t)f * 128], acc);
      acc = fmaxf(acc, 0.f);
      l0 = fmaf(acc, w2[((size_t)h * 128 + k) * 2], l0);
      l1 = fmaf(acc, w2[((size_t)h * 128 + k) * 2 + 1], l1);
    }
#pragma unroll
    for (int mm = 1; mm < 64; mm <<= 1) { l0 += __shfl_xor(l0, mm); l1 += __shfl_xor(l1, mm); }
    l0 += b2[h * 2]; l1 += b2[h * 2 + 1];
    float mx = fmaxf(l0, l1);
    float e0 = __expf(l0 - mx), e1 = __expf(l1 - mx);
    float inv = 1.f / (e0 + e1);
    wa0 += e0 * inv; wa1 += e1 * inv;
  }
  if (lane == 0) {
    wm[(size_t)n * 2] = wa0 * 0.125f;
    wm[(size_t)n * 2 + 1] = wa1 * 0.125f;
  }
}

// ===== b3 transforms + final conv + log_softmax =====
__global__ void k_b3_lit(const float* __restrict__ x2, const float* __restrict__ wl,
                         const float* __restrict__ wr,
                         float* __restrict__ xl3, float* __restrict__ xr3, int NB) {
  int n = blockIdx.x * blockDim.x + threadIdx.x;
  if (n >= NB) return;
  float l0 = 0.f, l1 = 0.f, r0 = 0.f, r1 = 0.f;
  for (int k = 0; k < 128; ++k) {
    float a = x2[(size_t)n * 128 + k];
    l0 = fmaf(a, wl[k * 2], l0);
    l1 = fmaf(a, wl[k * 2 + 1], l1);
    r0 = fmaf(a, wr[k * 2], r0);
    r1 = fmaf(a, wr[k * 2 + 1], r1);
  }
  xl3[(size_t)n * 2] = l0; xl3[(size_t)n * 2 + 1] = l1;
  xr3[(size_t)n * 2] = r0; xr3[(size_t)n * 2 + 1] = r1;
}

__global__ void k_final(const float* __restrict__ xl3, const float* __restrict__ logit,
                        const int* __restrict__ off, const int* __restrict__ srcl,
                        const float* __restrict__ Mx, const float* __restrict__ den,
                        const float* __restrict__ bias, float* __restrict__ out, int NB) {
  int n = blockIdx.x * blockDim.x + threadIdx.x;
  if (n >= NB) return;
  float m = Mx[n], dn = den[n];
  float c0 = 0.f, c1 = 0.f;
  int p0 = off[n], p1 = off[n + 1];
  for (int p = p0; p < p1; ++p) {
    int s = srcl[p];
    float pe = __expf(logit[p] - m);
    c0 = fmaf(pe, xl3[(size_t)s * 2], c0);
    c1 = fmaf(pe, xl3[(size_t)s * 2 + 1], c1);
  }
  float v0 = c0 / dn + bias[0];
  float v1 = c1 / dn + bias[1];
  float mx = fmaxf(v0, v1);
  float ls = mx + logf(__expf(v0 - mx) + __expf(v1 - mx));
  out[(size_t)n * 2] = v0 - ls;
  out[(size_t)n * 2 + 1] = v1 - ls;
}

// ===== sanity guard: max |cfeat| (f32) should be ~4.5 for N(0,1) =====
__global__ void k_maxabs_f(const float* __restrict__ p, long long n, int* __restrict__ slot) {
  long long i = (long long)blockIdx.x * blockDim.x + threadIdx.x;
  float v = 0.f;
  for (; i < n; i += (long long)gridDim.x * blockDim.x) v = fmaxf(v, fabsf(p[i]));
  atomicMax(slot, __float_as_int(v));
}
__global__ void k_guard(float* __restrict__ out, int out_size, const int* __restrict__ slot) {
  float m = __int_as_float(slot[0]);
  bool sane = (m >= 1.f && m <= 20.f);
  if (sane) return;
  int P = (m >= 0.f && m < 1e30f) ? min(999, (int)(10.f * m + 0.5f)) : 998;
  int i = blockIdx.x * blockDim.x + threadIdx.x;
  if (i < out_size) out[i] = (float)(1000 + P);
}

static inline int cdiv(int a, int b) { return (a + b - 1) / b; }

extern "C" void kernel_launch(void* const* d_in, const int* in_sizes, int n_in,
                              void* d_out, int out_size, void* d_ws, size_t ws_size,
                              hipStream_t stream) {
  (void)in_sizes; (void)n_in; (void)ws_size;
  // ROUND-9: float inputs are FLOAT32 (per harness contract), ints are int32.
  const float* bfeat = (const float*)d_in[0];
  const float* cfeat = (const float*)d_in[1];
  const int* bei = (const int*)d_in[2];
  const int* cei = (const int*)d_in[3];
  const int* b2c = (const int*)d_in[4];
  const float* c1_wl = (const float*)d_in[5];
  const float* c1_wr = (const float*)d_in[6];
  const float* c1_att = (const float*)d_in[7];
  const float* c1_b = (const float*)d_in[8];
  const float* c2_wl = (const float*)d_in[9];
  const float* c2_wr = (const float*)d_in[10];
  const float* c2_att = (const float*)d_in[11];
  const float* c2_b = (const float*)d_in[12];
  const float* fa_w1 = (const float*)d_in[13];
  const float* fa_b1 = (const float*)d_in[14];
  const float* fa_w2 = (const float*)d_in[15];
  const float* fa_b2 = (const float*)d_in[16];
  const float* b1_wl = (const float*)d_in[17];
  const float* b1_wr = (const float*)d_in[18];
  const float* b1_att = (const float*)d_in[19];
  const float* b1_b = (const float*)d_in[20];
  const float* b2_wl = (const float*)d_in[21];
  const float* b2_wr = (const float*)d_in[22];
  const float* b2_att = (const float*)d_in[23];
  const float* b2_b = (const float*)d_in[24];
  const float* b3_wl = (const float*)d_in[25];
  const float* b3_wr = (const float*)d_in[26];
  const float* b3_att = (const float*)d_in[27];
  const float* b3_b = (const float*)d_in[28];
  char* ws = (char*)d_ws;
  float* out = (float*)d_out;

  // reference convention: src = edge_index[0], dst = edge_index[1]
  const int* b_src_arr = bei;
  const int* b_dst_arr = bei + EBU;
  const int* c_src_arr = cei;
  const int* c_dst_arr = cei + ECO;

  float* XL2  = (float*)(ws + OFF_XL2);
  float* XR2  = (float*)(ws + OFF_XR2);
  float* XLH  = (float*)(ws + OFF_XLH);
  float* XRH  = (float*)(ws + OFF_XRH);
  float* X1C  = (float*)(ws + OFF_X1C);
  float* X2   = (float*)(ws + OFF_X2);
  float* CXL  = (float*)(ws + OFF_CXL);
  float* CXR  = (float*)(ws + OFF_CXR);
  float* CX1  = (float*)(ws + OFF_CX1);
  float* CX2L = (float*)(ws + OFF_CX2L);
  float* CX2R = (float*)(ws + OFF_CX2R);
  float* LOGC = (float*)(ws + OFF_LOGC);
  float* MC   = (float*)(ws + OFF_MC);
  float* DC   = (float*)(ws + OFF_DC);
  float* LOG2 = (float*)(ws + OFF_LOG2);
  float* M2   = (float*)(ws + OFF_M2);
  float* D2   = (float*)(ws + OFF_D2);
  float* CX2F = (float*)(ws + OFF_CX2F);
  float* WM   = (float*)(ws + OFF_WM);
  float* XL3  = (float*)(ws + OFF_XL3);
  float* XR3  = (float*)(ws + OFF_XR3);
  float* LOG1 = (float*)(ws + OFF_LOG1);
  float* M1   = (float*)(ws + OFF_M1);
  float* D1   = (float*)(ws + OFF_D1);
  int* BOFF = (int*)(ws + OFF_BOFF);
  int* BCUR = (int*)(ws + OFF_BCUR);
  int* BSRC = (int*)(ws + OFF_BSRC);
  int* COFF = (int*)(ws + OFF_COFF);
  int* CCUR = (int*)(ws + OFF_CCUR);
  int* CSRC = (int*)(ws + OFF_CSRC);
  int* BDST = (int*)(ws + OFF_BDST);
  int* CDST = (int*)(ws + OFF_CDST);
  int* STAT = (int*)(ws + OFF_STAT);

  k_zero<<<1, 4, 0, stream>>>(STAT, 4);

  // ---- CSR builds ----
  k_zero<<<cdiv(NBLD, 256), 256, 0, stream>>>(BCUR, NBLD);
  k_count<<<cdiv(EBT, 256), 256, 0, stream>>>(b_dst_arr, EBU, EBT, BCUR);
  k_scan_block<<<1, 256, 0, stream>>>(BCUR, NBLD, BOFF);
  k_copycur<<<cdiv(NBLD, 256), 256, 0, stream>>>(BOFF, BCUR, NBLD);
  k_scatter<<<cdiv(EBT, 256), 256, 0, stream>>>(b_src_arr, b_dst_arr, EBU, EBT, BCUR, BSRC, BDST);
  k_zero<<<cdiv(NCOM, 256), 256, 0, stream>>>(CCUR, NCOM);
  k_count<<<cdiv(ECT, 256), 256, 0, stream>>>(c_dst_arr, ECO, ECT, CCUR);
  k_scan_block<<<1, 256, 0, stream>>>(CCUR, NCOM, COFF);
  k_copycur<<<cdiv(NCOM, 256), 256, 0, stream>>>(COFF, CCUR, NCOM);
  k_scatter<<<cdiv(ECT, 256), 256, 0, stream>>>(c_src_arr, c_dst_arr, ECO, ECT, CCUR, CSRC, CDST);

  // ---- community GNN ----
  k_gemm_lit<0, false, false><<<cdiv(NCOM * 512, 256), 256, 0, stream>>>(
      cfeat, nullptr, nullptr, nullptr, nullptr, c1_wl, nullptr, CXL, nullptr,
      NCOM, 32, 32, 512, 512);
  k_gemm_lit<0, false, false><<<cdiv(NCOM * 512, 256), 256, 0, stream>>>(
      cfeat, nullptr, nullptr, nullptr, nullptr, c1_wr, nullptr, CXR, nullptr,
      NCOM, 32, 32, 512, 512);
  k_logit<8, 64><<<cdiv(ECT, 256), 256, 0, stream>>>(CXL, CXR, c1_att, CSRC, CDST, LOGC, ECT, 512);
  k_segmax<8><<<cdiv(NCOM, 256), 256, 0, stream>>>(LOGC, COFF, MC, NCOM);
  k_segden<8><<<cdiv(NCOM, 256), 256, 0, stream>>>(LOGC, COFF, MC, DC, NCOM);
  k_agg<8, 64, 8, true><<<cdiv(NCOM, 4), 256, 0, stream>>>(CXL, LOGC, COFF, CSRC, MC, DC, c1_b, CX1, NCOM, 512);
  k_gemm_lit<0, false, false><<<cdiv(NCOM * 128, 256), 256, 0, stream>>>(
      CX1, nullptr, nullptr, nullptr, nullptr, c2_wl, nullptr, CX2L, nullptr,
      NCOM, 512, 512, 128, 128);
  k_gemm_lit<0, false, false><<<cdiv(NCOM * 128, 256), 256, 0, stream>>>(
      CX1, nullptr, nullptr, nullptr, nullptr, c2_wr, nullptr, CX2R, nullptr,
      NCOM, 512, 512, 128, 128);
  k_logit<4, 32><<<cdiv(ECT, 256), 256, 0, stream>>>(CX2L, CX2R, c2_att, CSRC, CDST, LOGC, ECT, 128);
  k_segmax<4><<<cdiv(NCOM, 256), 256, 0, stream>>>(LOGC, COFF, MC, NCOM);
  k_segden<4><<<cdiv(NCOM, 256), 256, 0, stream>>>(LOGC, COFF, MC, DC, NCOM);
  k_agg<4, 32, 2, true><<<cdiv(NCOM, 4), 256, 0, stream>>>(CX2L, LOGC, COFF, CSRC, MC, DC, c2_b, CX2F, NCOM, 128);

  // ---- feature-attention fusion ----
  k_fa_lit<<<NBLD / 4, 256, 0, stream>>>(bfeat, CX2F, b2c, fa_w1, fa_b1, fa_w2, fa_b2, WM, NBLD);

  // ---- building conv1 chunks (per-head, two-pass softmax, K-partial into conv2 xl/xr) ----
  for (int c = 0; c < 8; ++c) {
    k_gemm_lit<2, true, false><<<cdiv(NBLD * 128, 256), 256, 0, stream>>>(
        nullptr, bfeat, CX2F, b2c, WM, b1_wl + c * 64, b1_wr + c * 64, XLH, XRH,
        NBLD, 192, 0, 512, 128);
    k_logit<1, 64><<<cdiv(EBT, 256), 256, 0, stream>>>(XLH, XRH, b1_att + c * 64, BSRC, BDST, LOG1, EBT, 64);
    k_segmax<1><<<cdiv(NBLD, 256), 256, 0, stream>>>(LOG1, BOFF, M1, NBLD);
    k_segden<1><<<cdiv(NBLD, 256), 256, 0, stream>>>(LOG1, BOFF, M1, D1, NBLD);
    k_agg<1, 64, 1, true><<<cdiv(NBLD, 4), 256, 0, stream>>>(XLH, LOG1, BOFF, BSRC, M1, D1, b1_b + c * 64, X1C, NBLD, 64);
    if (c == 0) {
      k_gemm_lit<0, false, false><<<cdiv(NBLD * 128, 256), 256, 0, stream>>>(
          X1C, nullptr, nullptr, nullptr, nullptr, b2_wl + (size_t)c * 64 * 128, nullptr, XL2, nullptr,
          NBLD, 64, 64, 128, 128);
      k_gemm_lit<0, false, false><<<cdiv(NBLD * 128, 256), 256, 0, stream>>>(
          X1C, nullptr, nullptr, nullptr, nullptr, b2_wr + (size_t)c * 64 * 128, nullptr, XR2, nullptr,
          NBLD, 64, 64, 128, 128);
    } else {
      k_gemm_lit<0, false, true><<<cdiv(NBLD * 128, 256), 256, 0, stream>>>(
          X1C, nullptr, nullptr, nullptr, nullptr, b2_wl + (size_t)c * 64 * 128, nullptr, XL2, nullptr,
          NBLD, 64, 64, 128, 128);
      k_gemm_lit<0, false, true><<<cdiv(NBLD * 128, 256), 256, 0, stream>>>(
          X1C, nullptr, nullptr, nullptr, nullptr, b2_wr + (size_t)c * 64 * 128, nullptr, XR2, nullptr,
          NBLD, 64, 64, 128, 128);
    }
  }

  // ---- building conv2 ----
  k_logit<4, 32><<<cdiv(EBT, 256), 256, 0, stream>>>(XL2, XR2, b2_att, BSRC, BDST, LOG2, EBT, 128);
  k_segmax<4><<<cdiv(NBLD, 256), 256, 0, stream>>>(LOG2, BOFF, M2, NBLD);
  k_segden<4><<<cdiv(NBLD, 256), 256, 0, stream>>>(LOG2, BOFF, M2, D2, NBLD);
  k_agg<4, 32, 2, true><<<cdiv(NBLD, 4), 256, 0, stream>>>(XL2, LOG2, BOFF, BSRC, M2, D2, b2_b, X2, NBLD, 128);

  // ---- conv3 + log_softmax ----
  k_b3_lit<<<cdiv(NBLD, 256), 256, 0, stream>>>(X2, b3_wl, b3_wr, XL3, XR3, NBLD);
  k_logit<1, 2><<<cdiv(EBT, 256), 256, 0, stream>>>(XL3, XR3, b3_att, BSRC, BDST, LOG1, EBT, 2);
  k_segmax<1><<<cdiv(NBLD, 256), 256, 0, stream>>>(LOG1, BOFF, M1, NBLD);
  k_segden<1><<<cdiv(NBLD, 256), 256, 0, stream>>>(LOG1, BOFF, M1, D1, NBLD);
  k_final<<<cdiv(NBLD, 256), 256, 0, stream>>>(XL3, LOG1, BOFF, BSRC, M1, D1, b3_b, out, NBLD);

  // ---- sanity guard (silent when inputs decode sanely as f32) ----
  k_maxabs_f<<<512, 256, 0, stream>>>(cfeat, (long long)NCOM * 32, STAT + 0);
  k_guard<<<cdiv(out_size, 256), 256, 0, stream>>>(out, out_size, STAT);
}

// Round 10
// 3327.833 us; speedup vs baseline: 5.9360x; 5.9360x over previous
//
#include <hip/hip_runtime.h>

static constexpr int NBLD = 100000, NCOM = 10000, EBU = 400000, ECO = 80000;
static constexpr int EBT = EBU + NBLD;   // 500000 (with self loops)
static constexpr int ECT = ECO + NCOM;   //  90000

// ---- workspace layout (bytes, f32 everywhere). Peak < 190 MB (195 proven safe). ----
static constexpr size_t OFF_XL2  = 0;              // [NB,128] conv2 xl accum
static constexpr size_t OFF_XR2  = 51200000;       // [NB,128]
static constexpr size_t OFF_XLH  = 102400000;      // [NB,64] chunk
static constexpr size_t OFF_XRH  = 128000000;      // [NB,64]
static constexpr size_t OFF_X1C  = 153600000;      // [NB,64]
static constexpr size_t OFF_X2   = 102400000;      // [NB,128] overlay (XLH/XRH dead)
// community overlay (front, dead before building stage):
static constexpr size_t OFF_CXL  = 0;              // [NC,512]
static constexpr size_t OFF_CXR  = 20480000;
static constexpr size_t OFF_CX1  = 40960000;
static constexpr size_t OFF_CX2L = 61440000;       // [NC,128]
static constexpr size_t OFF_CX2R = 66560000;
// persistent:
static constexpr size_t OFF_CX2F = 179200000;      // [NC,128]
static constexpr size_t OFF_WM   = 184320000;      // [NB,2]
static constexpr size_t OFF_XL3  = 185120000;      // [NB,2]
static constexpr size_t OFF_XR3  = 185920000;      // [NB,2]
static constexpr size_t OFF_BOFF = 186720000;      // (NB+1) int
static constexpr size_t OFF_BCUR = 187120016;      // NB int
static constexpr size_t OFF_BSRC = 187520016;      // EBT int
static constexpr size_t OFF_COFF = 189520016;      // (NC+1) int
static constexpr size_t OFF_CCUR = 189560032;      // NC int
static constexpr size_t OFF_CSRC = 189600032;      // ECT int
static constexpr size_t OFF_SC1  = 189960032;      // 256 int
static constexpr size_t OFF_SC2  = 189961056;      // 256 int
// end: ~189,962,080

// ================= small utils =================
__global__ void k_zero(int* __restrict__ p, int n) {
  int i = blockIdx.x * blockDim.x + threadIdx.x;
  if (i < n) p[i] = 0;
}

// ================= CSR build =================
__global__ void k_count(const int* __restrict__ dsti, int Eg, int Et, int* __restrict__ cnt) {
  int e = blockIdx.x * blockDim.x + threadIdx.x;
  if (e >= Et) return;
  int dst = (e < Eg) ? dsti[e] : (e - Eg);
  atomicAdd(&cnt[dst], 1);
}

__global__ void k_scan1(const int* __restrict__ cnt, int N, int* __restrict__ off, int* __restrict__ bsum) {
  __shared__ int sh[256];
  int tid = threadIdx.x;
  int base = blockIdx.x * 2048 + tid * 8;
  int c[8]; int s = 0;
#pragma unroll
  for (int j = 0; j < 8; ++j) { int i = base + j; c[j] = (i < N) ? cnt[i] : 0; s += c[j]; }
  sh[tid] = s; __syncthreads();
  int own = s;
  for (int o = 1; o < 256; o <<= 1) {
    int v = (tid >= o) ? sh[tid - o] : 0; __syncthreads();
    sh[tid] += v; __syncthreads();
  }
  int ex = sh[tid] - own;
#pragma unroll
  for (int j = 0; j < 8; ++j) { int i = base + j; if (i < N) off[i] = ex; ex += c[j]; }
  if (tid == 255) bsum[blockIdx.x] = sh[255];
}

__global__ void k_scan2(const int* __restrict__ bsum, int nb, int* __restrict__ bpre) {
  __shared__ int sh[256];
  int tid = threadIdx.x;
  int v0 = (tid < nb) ? bsum[tid] : 0;
  sh[tid] = v0; __syncthreads();
  for (int o = 1; o < 256; o <<= 1) {
    int v = (tid >= o) ? sh[tid - o] : 0; __syncthreads();
    sh[tid] += v; __syncthreads();
  }
  bpre[tid] = sh[tid] - v0;
}

__global__ void k_scan3(int* __restrict__ off, int N, const int* __restrict__ bpre, int Et) {
  int i = blockIdx.x * blockDim.x + threadIdx.x;
  if (i < N) off[i] += bpre[i >> 11];
  if (i == 0) off[N] = Et;
}

__global__ void k_copycur(const int* __restrict__ off, int* __restrict__ cur, int N) {
  int i = blockIdx.x * blockDim.x + threadIdx.x;
  if (i < N) cur[i] = off[i];
}

__global__ void k_scatter(const int* __restrict__ srci, const int* __restrict__ dsti, int Eg, int Et,
                          int* __restrict__ cur, int* __restrict__ srcl) {
  int e = blockIdx.x * blockDim.x + threadIdx.x;
  if (e >= Et) return;
  int src, dst;
  if (e < Eg) { src = srci[e]; dst = dsti[e]; } else { src = dst = e - Eg; }
  int pos = atomicAdd(&cur[dst], 1);
  srcl[pos] = src;
}

// ===== tiled GEMM (f32): 128x128 tile, 8x8/thread =====
// AMODE 0: A = af32 [M,lda]. AMODE 2: fused A (K=192): k<64 -> bfeat[n,k]*w0,
//          else cx2f[map[n],k-64]*w1 (wm==nullptr -> 1).
// PAIR: W0/W1 two 64-col slabs (row stride ldw); out0/out1 [M,64].
// ACCUM (non-PAIR): out0 +=.
template<int AMODE, bool PAIR, bool ACCUM>
__global__ __launch_bounds__(256) void k_gemm(
    const float* __restrict__ af32,
    const float* __restrict__ bfeat, const float* __restrict__ cx2f,
    const int* __restrict__ map, const float* __restrict__ wm,
    const float* __restrict__ W0, const float* __restrict__ W1,
    float* __restrict__ out0, float* __restrict__ out1,
    int M, int K, int lda, int ldw, int ldo) {
  __shared__ float As[16][132];
  __shared__ float Bs[16][132];
  int tid = threadIdx.x;
  int bm = blockIdx.y * 128, bn = blockIdx.x * 128;
  int tx = tid & 15, ty = tid >> 4;
  float acc[8][8] = {{0.f}};

  int arow = bm + (tid >> 1);
  int mrow = 0; float w0f = 1.f, w1f = 1.f;
  if (AMODE == 2 && arow < M) {
    mrow = map[arow];
    if (wm != nullptr) { w0f = wm[(size_t)arow * 2]; w1f = wm[(size_t)arow * 2 + 1]; }
  }

  for (int k0 = 0; k0 < K; k0 += 16) {
    {
      int row = tid >> 1;
      int colh = (tid & 1) * 8;
      int gr = bm + row;
#pragma unroll
      for (int q = 0; q < 2; ++q) {
        int gc = k0 + colh + q * 4;
        float4 f = make_float4(0.f, 0.f, 0.f, 0.f);
        if (gr < M) {
          if (AMODE == 0) {
            f = *(const float4*)(af32 + (size_t)gr * lda + gc);
          } else {
            if (gc < 64) {
              f = *(const float4*)(bfeat + (size_t)gr * 64 + gc);
              f.x *= w0f; f.y *= w0f; f.z *= w0f; f.w *= w0f;
            } else {
              f = *(const float4*)(cx2f + (size_t)mrow * 128 + (gc - 64));
              f.x *= w1f; f.y *= w1f; f.z *= w1f; f.w *= w1f;
            }
          }
        }
        int cb = colh + q * 4;
        As[cb + 0][row] = f.x; As[cb + 1][row] = f.y;
        As[cb + 2][row] = f.z; As[cb + 3][row] = f.w;
      }
    }
    {
      int r = tid >> 4;
      int c = (tid & 15) * 8;
#pragma unroll
      for (int q = 0; q < 2; ++q) {
        int gk = k0 + r;
        int gn = bn + c + q * 4;
        const float* wp;
        if (PAIR) wp = (gn < 64) ? (W0 + (size_t)gk * ldw + gn) : (W1 + (size_t)gk * ldw + (gn - 64));
        else      wp = W0 + (size_t)gk * ldw + gn;
        *(float4*)&Bs[r][c + q * 4] = *(const float4*)wp;
      }
    }
    __syncthreads();
#pragma unroll
    for (int kk = 0; kk < 16; ++kk) {
      float a[8], b[8];
#pragma unroll
      for (int i = 0; i < 8; ++i) a[i] = As[kk][ty * 8 + i];
#pragma unroll
      for (int j = 0; j < 8; ++j) b[j] = Bs[kk][tx * 8 + j];
#pragma unroll
      for (int i = 0; i < 8; ++i)
#pragma unroll
        for (int j = 0; j < 8; ++j) acc[i][j] = fmaf(a[i], b[j], acc[i][j]);
    }
    __syncthreads();
  }
#pragma unroll
  for (int i = 0; i < 8; ++i) {
    int row = bm + ty * 8 + i;
    if (row >= M) continue;
#pragma unroll
    for (int j = 0; j < 8; j += 4) {
      int col = bn + tx * 8 + j;
      float4 v = make_float4(acc[i][j], acc[i][j + 1], acc[i][j + 2], acc[i][j + 3]);
      if (PAIR) {
        float* o = (col < 64) ? out0 : out1;
        *(float4*)(o + (size_t)row * 64 + (col & 63)) = v;
      } else {
        float4* p = (float4*)(out0 + (size_t)row * ldo + col);
        if (ACCUM) {
          float4 old = *p;
          v.x += old.x; v.y += old.y; v.z += old.z; v.w += old.w;
        }
        *p = v;
      }
    }
  }
}

// ===== fused online-softmax GATv2 conv (CSR by dst, wave per node, f32) =====
// width = V*64 channels; G = lanes per head = head_dim/V.
template<int V, int G, bool RELU>
__global__ __launch_bounds__(256) void k_convf(const float* __restrict__ xl, const float* __restrict__ xr,
                                               const float* __restrict__ attw, const float* __restrict__ bias,
                                               const int* __restrict__ off, const int* __restrict__ srcl,
                                               float* __restrict__ outp, int N, int ldx, int ldo) {
  int n = (int)((blockIdx.x * (unsigned)blockDim.x + threadIdx.x) >> 6);
  if (n >= N) return;
  int lane = threadIdx.x & 63;
  int base = lane * V;
  float xr_r[V], att_r[V], acc[V];
#pragma unroll
  for (int j = 0; j < V; ++j) {
    xr_r[j] = xr[(size_t)n * ldx + base + j];
    att_r[j] = attw[base + j];
    acc[j] = 0.f;
  }
  float mh = -INFINITY, lh = 0.f;
  int p0 = off[n], p1 = off[n + 1];
  for (int p = p0; p < p1; ++p) {
    int src = srcl[p];
    float xlv[V];
#pragma unroll
    for (int j = 0; j < V; ++j) xlv[j] = xl[(size_t)src * ldx + base + j];
    float part = 0.f;
#pragma unroll
    for (int j = 0; j < V; ++j) {
      float t = xlv[j] + xr_r[j];
      t = t > 0.f ? t : 0.2f * t;          // leaky_relu(., 0.2)
      part = fmaf(t, att_r[j], part);
    }
#pragma unroll
    for (int m = 1; m < G; m <<= 1) part += __shfl_xor(part, m);
    float mn = fmaxf(mh, part);
    float scl = __expf(mh - mn);
    float pe = __expf(part - mn);
    lh = lh * scl + pe;
#pragma unroll
    for (int j = 0; j < V; ++j) acc[j] = acc[j] * scl + pe * xlv[j];
    mh = mn;
  }
  float inv = 1.f / lh;
#pragma unroll
  for (int j = 0; j < V; ++j) {
    float v = fmaf(acc[j], inv, bias[base + j]);
    if (RELU) v = fmaxf(v, 0.f);
    outp[(size_t)n * ldo + base + j] = v;
  }
}

// ===== fused feature-attention (tiled): wmean[n,2] from on-the-fly combined =====
// 256 threads / 64 rows per block. A tile f32 in LDS (49.2 KB) + Bs (8.4 KB).
__global__ __launch_bounds__(256) void k_fa_fused(const float* __restrict__ bfeat,
                                                  const float* __restrict__ cx2f, const int* __restrict__ map,
                                                  const float* __restrict__ w1, const float* __restrict__ b1,
                                                  const float* __restrict__ w2, const float* __restrict__ b2,
                                                  float* __restrict__ wm, int NB) {
  __shared__ float Af[192][64];
  __shared__ float Bs[16][132];
  int tid = threadIdx.x;
  int bm = blockIdx.x * 64;
  int tx = tid & 15, ty = tid >> 4;

  // stage combined [64 rows][192 cols] transposed into Af[col][row]
  {
    int r = tid >> 2;              // 64 rows
    int q4 = tid & 3;              // 4 quarters of 48 cols
    int gr = bm + r;
    int kb = q4 * 48;
    if (gr < NB) {
      int m = map[gr];
#pragma unroll
      for (int q = 0; q < 12; ++q) {
        int k = kb + q * 4;
        float4 f = (k < 64) ? *(const float4*)(bfeat + (size_t)gr * 64 + k)
                            : *(const float4*)(cx2f + (size_t)m * 128 + (k - 64));
        Af[k + 0][r] = f.x; Af[k + 1][r] = f.y; Af[k + 2][r] = f.z; Af[k + 3][r] = f.w;
      }
    } else {
#pragma unroll
      for (int q = 0; q < 12; ++q) {
        int k = kb + q * 4;
        Af[k + 0][r] = 0.f; Af[k + 1][r] = 0.f; Af[k + 2][r] = 0.f; Af[k + 3][r] = 0.f;
      }
    }
  }
  __syncthreads();

  float wa0[4], wa1[4];
#pragma unroll
  for (int i = 0; i < 4; ++i) { wa0[i] = 0.f; wa1[i] = 0.f; }

  for (int h = 0; h < 8; ++h) {
    float acc[4][8];
#pragma unroll
    for (int i = 0; i < 4; ++i)
#pragma unroll
      for (int j = 0; j < 8; ++j) acc[i][j] = 0.f;

    for (int k0 = 0; k0 < 192; k0 += 16) {
      {
        int r = tid >> 4;
        int c = (tid & 15) * 8;
#pragma unroll
        for (int q = 0; q < 2; ++q)
          *(float4*)&Bs[r][c + q * 4] =
              *(const float4*)(w1 + ((size_t)h * 192 + k0 + r) * 128 + c + q * 4);
      }
      __syncthreads();
#pragma unroll
      for (int kk = 0; kk < 16; ++kk) {
        float a[4], b[8];
#pragma unroll
        for (int i = 0; i < 4; ++i) a[i] = Af[k0 + kk][ty * 4 + i];
#pragma unroll
        for (int j = 0; j < 8; ++j) b[j] = Bs[kk][tx * 8 + j];
#pragma unroll
        for (int i = 0; i < 4; ++i)
#pragma unroll
          for (int j = 0; j < 8; ++j) acc[i][j] = fmaf(a[i], b[j], acc[i][j]);
      }
      __syncthreads();
    }

    // epilogue: relu(acc + b1) -> 2-logit matvec -> reduce over 16 tx lanes -> softmax
    float b1v[8], w20[8], w21[8];
#pragma unroll
    for (int j = 0; j < 8; ++j) {
      int col = tx * 8 + j;
      b1v[j] = b1[h * 128 + col];
      w20[j] = w2[((size_t)h * 128 + col) * 2];
      w21[j] = w2[((size_t)h * 128 + col) * 2 + 1];
    }
    float b2h0 = b2[h * 2], b2h1 = b2[h * 2 + 1];
#pragma unroll
    for (int i = 0; i < 4; ++i) {
      float s0 = 0.f, s1 = 0.f;
#pragma unroll
      for (int j = 0; j < 8; ++j) {
        float hv = fmaxf(acc[i][j] + b1v[j], 0.f);
        s0 = fmaf(hv, w20[j], s0);
        s1 = fmaf(hv, w21[j], s1);
      }
#pragma unroll
      for (int m = 1; m < 16; m <<= 1) { s0 += __shfl_xor(s0, m); s1 += __shfl_xor(s1, m); }
      if (tx == 0) {
        float l0 = s0 + b2h0, l1 = s1 + b2h1;
        float mx = fmaxf(l0, l1);
        float e0 = __expf(l0 - mx), e1 = __expf(l1 - mx);
        float inv = 1.f / (e0 + e1);
        wa0[i] += e0 * inv;
        wa1[i] += e1 * inv;
      }
    }
  }
  if (tx == 0) {
#pragma unroll
    for (int i = 0; i < 4; ++i) {
      int row = bm + ty * 4 + i;
      if (row < NB) {
        wm[(size_t)row * 2] = wa0[i] * 0.125f;
        wm[(size_t)row * 2 + 1] = wa1[i] * 0.125f;
      }
    }
  }
}

// ===== b3 transforms (wave per node) + fused conv3 + log_softmax =====
__global__ __launch_bounds__(256) void k_b3gemm(const float* __restrict__ x2, const float* __restrict__ wl,
                                                const float* __restrict__ wr,
                                                float* __restrict__ xl3, float* __restrict__ xr3, int NB) {
  int n = (int)((blockIdx.x * (unsigned)blockDim.x + threadIdx.x) >> 6);
  if (n >= NB) return;
  int lane = threadIdx.x & 63;
  float2 a = *(const float2*)(x2 + (size_t)n * 128 + lane * 2);
  float4 wlv = *(const float4*)(wl + lane * 4);   // rows lane*2, lane*2+1 of [128,2]
  float4 wrv = *(const float4*)(wr + lane * 4);
  float l0 = a.x * wlv.x + a.y * wlv.z;
  float l1 = a.x * wlv.y + a.y * wlv.w;
  float r0 = a.x * wrv.x + a.y * wrv.z;
  float r1 = a.x * wrv.y + a.y * wrv.w;
#pragma unroll
  for (int m = 1; m < 64; m <<= 1) {
    l0 += __shfl_xor(l0, m); l1 += __shfl_xor(l1, m);
    r0 += __shfl_xor(r0, m); r1 += __shfl_xor(r1, m);
  }
  if (lane == 0) {
    xl3[(size_t)n * 2] = l0; xl3[(size_t)n * 2 + 1] = l1;
    xr3[(size_t)n * 2] = r0; xr3[(size_t)n * 2 + 1] = r1;
  }
}

__global__ void k_conv3(const float* __restrict__ xl, const float* __restrict__ xr,
                        const float* __restrict__ att, const float* __restrict__ bias,
                        const int* __restrict__ off, const int* __restrict__ srcl,
                        float* __restrict__ out, int NB) {
  int n = blockIdx.x * blockDim.x + threadIdx.x;
  if (n >= NB) return;
  float a0 = att[0], a1 = att[1];
  float xr0 = xr[(size_t)n * 2], xr1 = xr[(size_t)n * 2 + 1];
  float mh = -INFINITY, lh = 0.f, c0 = 0.f, c1 = 0.f;
  int p0 = off[n], p1 = off[n + 1];
  for (int p = p0; p < p1; ++p) {
    int src = srcl[p];
    float sl0 = xl[(size_t)src * 2], sl1 = xl[(size_t)src * 2 + 1];
    float t0 = sl0 + xr0; t0 = t0 > 0.f ? t0 : 0.2f * t0;
    float t1 = sl1 + xr1; t1 = t1 > 0.f ? t1 : 0.2f * t1;
    float lg = t0 * a0 + t1 * a1;
    float mn = fmaxf(mh, lg);
    float scl = __expf(mh - mn);
    float pe = __expf(lg - mn);
    lh = lh * scl + pe;
    c0 = c0 * scl + pe * sl0;
    c1 = c1 * scl + pe * sl1;
    mh = mn;
  }
  float inv = 1.f / lh;
  float v0 = c0 * inv + bias[0];
  float v1 = c1 * inv + bias[1];
  float mx = fmaxf(v0, v1);
  float ls = mx + logf(__expf(v0 - mx) + __expf(v1 - mx));
  out[(size_t)n * 2] = v0 - ls;
  out[(size_t)n * 2 + 1] = v1 - ls;
}

static inline int cdiv(int a, int b) { return (a + b - 1) / b; }

extern "C" void kernel_launch(void* const* d_in, const int* in_sizes, int n_in,
                              void* d_out, int out_size, void* d_ws, size_t ws_size,
                              hipStream_t stream) {
  (void)in_sizes; (void)n_in; (void)out_size; (void)ws_size;
  const float* bfeat = (const float*)d_in[0];
  const float* cfeat = (const float*)d_in[1];
  const int* bei = (const int*)d_in[2];
  const int* cei = (const int*)d_in[3];
  const int* b2c = (const int*)d_in[4];
  const float* c1_wl = (const float*)d_in[5];
  const float* c1_wr = (const float*)d_in[6];
  const float* c1_att = (const float*)d_in[7];
  const float* c1_b = (const float*)d_in[8];
  const float* c2_wl = (const float*)d_in[9];
  const float* c2_wr = (const float*)d_in[10];
  const float* c2_att = (const float*)d_in[11];
  const float* c2_b = (const float*)d_in[12];
  const float* fa_w1 = (const float*)d_in[13];
  const float* fa_b1 = (const float*)d_in[14];
  const float* fa_w2 = (const float*)d_in[15];
  const float* fa_b2 = (const float*)d_in[16];
  const float* b1_wl = (const float*)d_in[17];
  const float* b1_wr = (const float*)d_in[18];
  const float* b1_att = (const float*)d_in[19];
  const float* b1_b = (const float*)d_in[20];
  const float* b2_wl = (const float*)d_in[21];
  const float* b2_wr = (const float*)d_in[22];
  const float* b2_att = (const float*)d_in[23];
  const float* b2_b = (const float*)d_in[24];
  const float* b3_wl = (const float*)d_in[25];
  const float* b3_wr = (const float*)d_in[26];
  const float* b3_att = (const float*)d_in[27];
  const float* b3_b = (const float*)d_in[28];
  char* ws = (char*)d_ws;
  float* out = (float*)d_out;

  // reference convention: src = edge_index[0], dst = edge_index[1]
  const int* b_src_arr = bei;
  const int* b_dst_arr = bei + EBU;
  const int* c_src_arr = cei;
  const int* c_dst_arr = cei + ECO;

  float* XL2  = (float*)(ws + OFF_XL2);
  float* XR2  = (float*)(ws + OFF_XR2);
  float* XLH  = (float*)(ws + OFF_XLH);
  float* XRH  = (float*)(ws + OFF_XRH);
  float* X1C  = (float*)(ws + OFF_X1C);
  float* X2   = (float*)(ws + OFF_X2);
  float* CXL  = (float*)(ws + OFF_CXL);
  float* CXR  = (float*)(ws + OFF_CXR);
  float* CX1  = (float*)(ws + OFF_CX1);
  float* CX2L = (float*)(ws + OFF_CX2L);
  float* CX2R = (float*)(ws + OFF_CX2R);
  float* CX2F = (float*)(ws + OFF_CX2F);
  float* WM   = (float*)(ws + OFF_WM);
  float* XL3  = (float*)(ws + OFF_XL3);
  float* XR3  = (float*)(ws + OFF_XR3);
  int* BOFF = (int*)(ws + OFF_BOFF);
  int* BCUR = (int*)(ws + OFF_BCUR);
  int* BSRC = (int*)(ws + OFF_BSRC);
  int* COFF = (int*)(ws + OFF_COFF);
  int* CCUR = (int*)(ws + OFF_CCUR);
  int* CSRC = (int*)(ws + OFF_CSRC);
  int* SC1  = (int*)(ws + OFF_SC1);
  int* SC2  = (int*)(ws + OFF_SC2);

  // ---- CSR: building graph ----
  k_zero<<<cdiv(NBLD, 256), 256, 0, stream>>>(BCUR, NBLD);
  k_count<<<cdiv(EBT, 256), 256, 0, stream>>>(b_dst_arr, EBU, EBT, BCUR);
  k_scan1<<<cdiv(NBLD, 2048), 256, 0, stream>>>(BCUR, NBLD, BOFF, SC1);
  k_scan2<<<1, 256, 0, stream>>>(SC1, cdiv(NBLD, 2048), SC2);
  k_scan3<<<cdiv(NBLD, 256), 256, 0, stream>>>(BOFF, NBLD, SC2, EBT);
  k_copycur<<<cdiv(NBLD, 256), 256, 0, stream>>>(BOFF, BCUR, NBLD);
  k_scatter<<<cdiv(EBT, 256), 256, 0, stream>>>(b_src_arr, b_dst_arr, EBU, EBT, BCUR, BSRC);
  // ---- CSR: community graph ----
  k_zero<<<cdiv(NCOM, 256), 256, 0, stream>>>(CCUR, NCOM);
  k_count<<<cdiv(ECT, 256), 256, 0, stream>>>(c_dst_arr, ECO, ECT, CCUR);
  k_scan1<<<cdiv(NCOM, 2048), 256, 0, stream>>>(CCUR, NCOM, COFF, SC1);
  k_scan2<<<1, 256, 0, stream>>>(SC1, cdiv(NCOM, 2048), SC2);
  k_scan3<<<cdiv(NCOM, 256), 256, 0, stream>>>(COFF, NCOM, SC2, ECT);
  k_copycur<<<cdiv(NCOM, 256), 256, 0, stream>>>(COFF, CCUR, NCOM);
  k_scatter<<<cdiv(ECT, 256), 256, 0, stream>>>(c_src_arr, c_dst_arr, ECO, ECT, CCUR, CSRC);

  // ---- community GNN ----
  k_gemm<0, false, false><<<dim3(4, cdiv(NCOM, 128)), 256, 0, stream>>>(
      cfeat, nullptr, nullptr, nullptr, nullptr, c1_wl, nullptr, CXL, nullptr, NCOM, 32, 32, 512, 512);
  k_gemm<0, false, false><<<dim3(4, cdiv(NCOM, 128)), 256, 0, stream>>>(
      cfeat, nullptr, nullptr, nullptr, nullptr, c1_wr, nullptr, CXR, nullptr, NCOM, 32, 32, 512, 512);
  k_convf<8, 8, true><<<cdiv(NCOM, 4), 256, 0, stream>>>(CXL, CXR, c1_att, c1_b, COFF, CSRC, CX1, NCOM, 512, 512);
  k_gemm<0, false, false><<<dim3(1, cdiv(NCOM, 128)), 256, 0, stream>>>(
      CX1, nullptr, nullptr, nullptr, nullptr, c2_wl, nullptr, CX2L, nullptr, NCOM, 512, 512, 128, 128);
  k_gemm<0, false, false><<<dim3(1, cdiv(NCOM, 128)), 256, 0, stream>>>(
      CX1, nullptr, nullptr, nullptr, nullptr, c2_wr, nullptr, CX2R, nullptr, NCOM, 512, 512, 128, 128);
  k_convf<2, 16, true><<<cdiv(NCOM, 4), 256, 0, stream>>>(CX2L, CX2R, c2_att, c2_b, COFF, CSRC, CX2F, NCOM, 128, 128);

  // ---- feature-attention fusion (tiled, fused) ----
  k_fa_fused<<<cdiv(NBLD, 64), 256, 0, stream>>>(bfeat, CX2F, b2c, fa_w1, fa_b1, fa_w2, fa_b2, WM, NBLD);

  // ---- building conv1: per-head chunks + K-partial accumulation into conv2 xl/xr ----
  for (int c = 0; c < 8; ++c) {
    k_gemm<2, true, false><<<dim3(1, cdiv(NBLD, 128)), 256, 0, stream>>>(
        nullptr, bfeat, CX2F, b2c, WM, b1_wl + c * 64, b1_wr + c * 64, XLH, XRH, NBLD, 192, 0, 512, 64);
    k_convf<1, 64, true><<<cdiv(NBLD, 4), 256, 0, stream>>>(XLH, XRH, b1_att + c * 64, b1_b + c * 64,
                                                            BOFF, BSRC, X1C, NBLD, 64, 64);
    if (c == 0) {
      k_gemm<0, false, false><<<dim3(1, cdiv(NBLD, 128)), 256, 0, stream>>>(
          X1C, nullptr, nullptr, nullptr, nullptr, b2_wl + (size_t)c * 64 * 128, nullptr, XL2, nullptr,
          NBLD, 64, 64, 128, 128);
      k_gemm<0, false, false><<<dim3(1, cdiv(NBLD, 128)), 256, 0, stream>>>(
          X1C, nullptr, nullptr, nullptr, nullptr, b2_wr + (size_t)c * 64 * 128, nullptr, XR2, nullptr,
          NBLD, 64, 64, 128, 128);
    } else {
      k_gemm<0, false, true><<<dim3(1, cdiv(NBLD, 128)), 256, 0, stream>>>(
          X1C, nullptr, nullptr, nullptr, nullptr, b2_wl + (size_t)c * 64 * 128, nullptr, XL2, nullptr,
          NBLD, 64, 64, 128, 128);
      k_gemm<0, false, true><<<dim3(1, cdiv(NBLD, 128)), 256, 0, stream>>>(
          X1C, nullptr, nullptr, nullptr, nullptr, b2_wr + (size_t)c * 64 * 128, nullptr, XR2, nullptr,
          NBLD, 64, 64, 128, 128);
    }
  }

  // ---- building conv2 ----
  k_convf<2, 16, true><<<cdiv(NBLD, 4), 256, 0, stream>>>(XL2, XR2, b2_att, b2_b, BOFF, BSRC, X2, NBLD, 128, 128);

  // ---- conv3 + log_softmax ----
  k_b3gemm<<<cdiv(NBLD, 4), 256, 0, stream>>>(X2, b3_wl, b3_wr, XL3, XR3, NBLD);
  k_conv3<<<cdiv(NBLD, 256), 256, 0, stream>>>(XL3, XR3, b3_att, b3_b, BOFF, BSRC, out, NBLD);
}